// Round 1
// baseline (392.785 us; speedup 1.0000x reference)
//
#include <hip/hip_runtime.h>

// ---------------------------------------------------------------------------
// LinearTimeCrossAttention, fully fused algebraically:
//   final[b] = A[b] @ x[b] + bias[b]   with A[b] 256x256 built from
//   w_out @ context[b]^T @ w_q  scaled by the GroupNorm affine.
// ---------------------------------------------------------------------------

// K1: GroupNorm stats: one block per (b,g); 8 channels x 4096 pixels contiguous.
__global__ __launch_bounds__(256) void gn_stats_kernel(const float* __restrict__ x,
                                                       float* __restrict__ stats) {
    int bg = blockIdx.x;  // b*32 + g
    const float4* xp = (const float4*)(x + (size_t)bg * 32768);
    float s = 0.f, ss = 0.f;
    for (int i = threadIdx.x; i < 8192; i += 256) {
        float4 v = xp[i];
        s  += v.x + v.y + v.z + v.w;
        ss += v.x*v.x + v.y*v.y + v.z*v.z + v.w*v.w;
    }
    #pragma unroll
    for (int off = 32; off > 0; off >>= 1) {
        s  += __shfl_down(s, off, 64);
        ss += __shfl_down(ss, off, 64);
    }
    __shared__ float ls[4], lss[4];
    int wave = threadIdx.x >> 6;
    if ((threadIdx.x & 63) == 0) { ls[wave] = s; lss[wave] = ss; }
    __syncthreads();
    if (threadIdx.x == 0) {
        float S  = ls[0] + ls[1] + ls[2] + ls[3];
        float SS = lss[0] + lss[1] + lss[2] + lss[3];
        float mean = S * (1.f / 32768.f);
        float var  = SS * (1.f / 32768.f) - mean * mean;
        stats[bg * 2]     = mean;
        stats[bg * 2 + 1] = rsqrtf(var + 1e-5f);
    }
}

// K2: kv[b,o,n] = sum_c w_kv[o,c]*cond[b,c,n] + b_kv[o]
// grid (n_tiles=16, o_tiles=16, B=16), block 256. o-tile 16, n-tile 64.
__global__ __launch_bounds__(256) void kv_kernel(const float* __restrict__ cond,
                                                 const float* __restrict__ w_kv,
                                                 const float* __restrict__ b_kv,
                                                 float* __restrict__ kv) {
    __shared__ float wl[16][512];  // 32 KB
    int b  = blockIdx.z;
    int ob = blockIdx.y * 16;
    int nb = blockIdx.x * 64;
    for (int i = threadIdx.x; i < 16 * 512; i += 256) {
        int r = i >> 9, c = i & 511;
        wl[r][c] = w_kv[(ob + r) * 512 + c];
    }
    __syncthreads();
    int tn = threadIdx.x & 63;
    int to = threadIdx.x >> 6;  // 0..3, uniform per wave -> LDS broadcast
    const float* cp = cond + (size_t)b * 512 * 1024 + nb + tn;
    float acc[4] = {0.f, 0.f, 0.f, 0.f};
    for (int c = 0; c < 512; ++c) {
        float cv = cp[(size_t)c * 1024];
        #pragma unroll
        for (int i = 0; i < 4; ++i)
            acc[i] += wl[to * 4 + i][c] * cv;
    }
    #pragma unroll
    for (int i = 0; i < 4; ++i) {
        int o = ob + to * 4 + i;
        kv[((size_t)b * 256 + o) * 1024 + nb + tn] = acc[i] + b_kv[o];
    }
}

// K3: per (b,h): softmax(k rows over 1024) then context[d,e] = sum_n p[d,n] v[e,n]
// 64 blocks x 256 threads.
__global__ __launch_bounds__(256) void ctx_kernel(const float* __restrict__ kv,
                                                  float* __restrict__ ctx) {
    int b = blockIdx.x >> 2, h = blockIdx.x & 3;
    const float* kp = kv + ((size_t)b * 256 + h * 32) * 1024;
    const float* vp = kv + ((size_t)b * 256 + 128 + h * 32) * 1024;
    __shared__ float rmax[32], rsum[32];
    __shared__ float pl[32][65], vl[32][65];
    int d = threadIdx.x >> 3, l = threadIdx.x & 7;
    float m = -INFINITY;
    for (int j = l; j < 1024; j += 8) m = fmaxf(m, kp[d * 1024 + j]);
    m = fmaxf(m, __shfl_xor(m, 1, 64));
    m = fmaxf(m, __shfl_xor(m, 2, 64));
    m = fmaxf(m, __shfl_xor(m, 4, 64));
    if (l == 0) rmax[d] = m;
    __syncthreads();
    m = rmax[d];
    float s = 0.f;
    for (int j = l; j < 1024; j += 8) s += expf(kp[d * 1024 + j] - m);
    s += __shfl_xor(s, 1, 64);
    s += __shfl_xor(s, 2, 64);
    s += __shfl_xor(s, 4, 64);
    if (l == 0) rsum[d] = s;

    float acc[4] = {0.f, 0.f, 0.f, 0.f};
    int dd[4], ee[4];
    #pragma unroll
    for (int i = 0; i < 4; ++i) {
        int idx = threadIdx.x + 256 * i;
        dd[i] = idx >> 5;
        ee[i] = idx & 31;
    }
    for (int n0 = 0; n0 < 1024; n0 += 64) {
        __syncthreads();
        for (int i = threadIdx.x; i < 2048; i += 256) {
            int r = i >> 6, nn = i & 63;
            pl[r][nn] = expf(kp[r * 1024 + n0 + nn] - rmax[r]) / rsum[r];
            vl[r][nn] = vp[r * 1024 + n0 + nn];
        }
        __syncthreads();
        #pragma unroll 8
        for (int nn = 0; nn < 64; ++nn) {
            #pragma unroll
            for (int i = 0; i < 4; ++i)
                acc[i] += pl[dd[i]][nn] * vl[ee[i]][nn];
        }
    }
    #pragma unroll
    for (int i = 0; i < 4; ++i)
        ctx[((size_t)blockIdx.x * 32 + dd[i]) * 32 + ee[i]] = acc[i];
}

// K4a: M[b][o][hd] = sum_e w_out[o, h*32+e] * ctx[b,h,d,e], hd = h*32+d
// grid B*128, block 256 (one thread per output).
__global__ __launch_bounds__(256) void m_kernel(const float* __restrict__ w_out,
                                                const float* __restrict__ ctx,
                                                float* __restrict__ M) {
    int b   = blockIdx.x >> 7;
    int idx = (blockIdx.x & 127) * 256 + threadIdx.x;  // 0..32767
    int o = idx >> 7, hd = idx & 127;
    int h = hd >> 5, d = hd & 31;
    const float* cp = ctx + (((size_t)b * 4 + h) * 32 + d) * 32;
    const float* wp = w_out + o * 128 + h * 32;
    float acc = 0.f;
    #pragma unroll
    for (int e = 0; e < 32; ++e) acc += wp[e] * cp[e];
    M[((size_t)b * 256 + o) * 128 + hd] = acc;
}

// K4b: per (b,o): A[b,o,c] = (sum_hd M[b,o,hd] w_q[hd,c]) * s[b,c]
//      bias[b,o]  = sum_c Wt[o,c]*t[b,c] + M[b,o,:]·b_q + b_out[o]
// grid B*256 blocks, 256 threads (c).
__global__ __launch_bounds__(256) void a_kernel(const float* __restrict__ M,
                                                const float* __restrict__ w_q,
                                                const float* __restrict__ b_q,
                                                const float* __restrict__ stats,
                                                const float* __restrict__ gn_w,
                                                const float* __restrict__ gn_b,
                                                const float* __restrict__ b_out,
                                                float* __restrict__ A,
                                                float* __restrict__ bias) {
    int b = blockIdx.x >> 8, o = blockIdx.x & 255;
    __shared__ float ml[128];
    __shared__ float red[256];
    const float* mp = M + ((size_t)b * 256 + o) * 128;
    if (threadIdx.x < 128) ml[threadIdx.x] = mp[threadIdx.x];
    __syncthreads();
    int c = threadIdx.x;
    float wt = 0.f;
    #pragma unroll 8
    for (int hd = 0; hd < 128; ++hd) wt += ml[hd] * w_q[hd * 256 + c];
    int g = c >> 3;
    float mu   = stats[(b * 32 + g) * 2];
    float rstd = stats[(b * 32 + g) * 2 + 1];
    float sc = rstd * gn_w[c];
    float tc = gn_b[c] - mu * sc;
    A[(size_t)blockIdx.x * 256 + c] = wt * sc;
    float contrib = wt * tc;
    if (threadIdx.x < 128) contrib += ml[threadIdx.x] * b_q[threadIdx.x];
    red[threadIdx.x] = contrib;
    __syncthreads();
    for (int s2 = 128; s2 > 0; s2 >>= 1) {
        if (threadIdx.x < s2) red[threadIdx.x] += red[threadIdx.x + s2];
        __syncthreads();
    }
    if (threadIdx.x == 0) bias[blockIdx.x] = red[0] + b_out[o];
}

// K5: out[b,o,n] = sum_c A[b,o,c]*x[b,c,n] + bias[b,o]
// grid (4096/128, 256/64, B); block 256; per-thread 8x4 outputs.
__global__ __launch_bounds__(256) void out_kernel(const float* __restrict__ x,
                                                  const float* __restrict__ A,
                                                  const float* __restrict__ bias,
                                                  float* __restrict__ out) {
    __shared__ float alT[32][68];   // [cc][o], pad 68 (272B rows, 16B aligned)
    __shared__ float xl[32][128];   // [cc][n]
    int b  = blockIdx.z;
    int ob = blockIdx.y * 64;
    int nb = blockIdx.x * 128;
    int t  = threadIdx.x;
    int cg = t & 31;   // n = nb + cg*4 + ni
    int rg = t >> 5;   // o = ob + rg*8 + oi
    float acc[8][4];
    #pragma unroll
    for (int i = 0; i < 8; ++i)
        #pragma unroll
        for (int j = 0; j < 4; ++j) acc[i][j] = 0.f;
    const float* Ab = A + ((size_t)b * 256 + ob) * 256;
    const float* xb = x + (size_t)b * 256 * 4096 + nb;
    for (int c0 = 0; c0 < 256; c0 += 32) {
        __syncthreads();
        #pragma unroll
        for (int j = 0; j < 8; ++j) {
            int e = t + 256 * j;
            int r = e >> 5, cc = e & 31;
            alT[cc][r] = Ab[r * 256 + c0 + cc];
        }
        #pragma unroll
        for (int j = 0; j < 4; ++j) {
            int e  = t + 256 * j;           // 1024 float4 slots
            int cc = e >> 5, nn = (e & 31) * 4;
            *(float4*)&xl[cc][nn] = *(const float4*)&xb[(size_t)(c0 + cc) * 4096 + nn];
        }
        __syncthreads();
        #pragma unroll
        for (int cc = 0; cc < 32; ++cc) {
            float4 xv = *(float4*)&xl[cc][cg * 4];
            float4 a0 = *(float4*)&alT[cc][rg * 8];
            float4 a1 = *(float4*)&alT[cc][rg * 8 + 4];
            float av[8] = {a0.x, a0.y, a0.z, a0.w, a1.x, a1.y, a1.z, a1.w};
            #pragma unroll
            for (int oi = 0; oi < 8; ++oi) {
                acc[oi][0] += av[oi] * xv.x;
                acc[oi][1] += av[oi] * xv.y;
                acc[oi][2] += av[oi] * xv.z;
                acc[oi][3] += av[oi] * xv.w;
            }
        }
    }
    #pragma unroll
    for (int oi = 0; oi < 8; ++oi) {
        int o = ob + rg * 8 + oi;
        float bv = bias[b * 256 + o];
        float4 r;
        r.x = acc[oi][0] + bv;
        r.y = acc[oi][1] + bv;
        r.z = acc[oi][2] + bv;
        r.w = acc[oi][3] + bv;
        *(float4*)&out[((size_t)b * 256 + o) * 4096 + nb + cg * 4] = r;
    }
}

extern "C" void kernel_launch(void* const* d_in, const int* in_sizes, int n_in,
                              void* d_out, int out_size, void* d_ws, size_t ws_size,
                              hipStream_t stream) {
    const float* x     = (const float*)d_in[0];
    const float* cond  = (const float*)d_in[1];
    const float* gn_w  = (const float*)d_in[2];
    const float* gn_b  = (const float*)d_in[3];
    const float* w_q   = (const float*)d_in[4];
    const float* b_q   = (const float*)d_in[5];
    const float* w_kv  = (const float*)d_in[6];
    const float* b_kv  = (const float*)d_in[7];
    const float* w_out = (const float*)d_in[8];
    const float* b_out = (const float*)d_in[9];
    float* out = (float*)d_out;

    float* ws    = (float*)d_ws;
    float* stats = ws;                  // 1024 floats
    float* kv    = ws + 1024;           // 16*256*1024 = 4194304
    float* ctx   = kv + 4194304;        // 16*4*32*32 = 65536
    float* M     = ctx + 65536;         // 16*256*128 = 524288
    float* A     = M + 524288;          // 16*256*256 = 1048576
    float* bias  = A + 1048576;         // 16*256 = 4096
    // total ~23.4 MB of d_ws

    gn_stats_kernel<<<512, 256, 0, stream>>>(x, stats);
    kv_kernel<<<dim3(16, 16, 16), 256, 0, stream>>>(cond, w_kv, b_kv, kv);
    ctx_kernel<<<64, 256, 0, stream>>>(kv, ctx);
    m_kernel<<<2048, 256, 0, stream>>>(w_out, ctx, M);
    a_kernel<<<4096, 256, 0, stream>>>(M, w_q, b_q, stats, gn_w, gn_b, b_out, A, bias);
    out_kernel<<<dim3(32, 4, 16), 256, 0, stream>>>(x, A, bias, out);
}

// Round 3
// 143.719 us; speedup vs baseline: 2.7330x; 2.7330x over previous
//
#include <hip/hip_runtime.h>
#include <hip/hip_bf16.h>

typedef __attribute__((ext_vector_type(8))) short bf16x8;
typedef __attribute__((ext_vector_type(4))) float f32x4;

__device__ __forceinline__ ushort f2bf(float f) {
    __hip_bfloat16 h = __float2bfloat16(f);
    return __builtin_bit_cast(ushort, h);
}
__device__ __forceinline__ float bflo(unsigned u) { return __uint_as_float(u << 16); }
__device__ __forceinline__ float bfhi(unsigned u) { return __uint_as_float(u & 0xffff0000u); }

__device__ __forceinline__ void gload16(const void* g, void* l) {
    __builtin_amdgcn_global_load_lds(
        (const __attribute__((address_space(1))) unsigned*)g,
        (__attribute__((address_space(3))) unsigned*)l,
        16, 0, 0);
}

// ---------------------------------------------------------------------------
// K1: GroupNorm stats per (b,g): 8 channels x 4096 pixels contiguous.
__global__ __launch_bounds__(256) void gn_stats_kernel(const float* __restrict__ x,
                                                       float* __restrict__ stats) {
    int bg = blockIdx.x;
    const float4* xp = (const float4*)(x + (size_t)bg * 32768);
    float s = 0.f, ss = 0.f;
    for (int i = threadIdx.x; i < 8192; i += 256) {
        float4 v = xp[i];
        s  += v.x + v.y + v.z + v.w;
        ss += v.x*v.x + v.y*v.y + v.z*v.z + v.w*v.w;
    }
    #pragma unroll
    for (int off = 32; off > 0; off >>= 1) {
        s  += __shfl_down(s, off, 64);
        ss += __shfl_down(ss, off, 64);
    }
    __shared__ float ls[4], lss[4];
    int wave = threadIdx.x >> 6;
    if ((threadIdx.x & 63) == 0) { ls[wave] = s; lss[wave] = ss; }
    __syncthreads();
    if (threadIdx.x == 0) {
        float S  = ls[0] + ls[1] + ls[2] + ls[3];
        float SS = lss[0] + lss[1] + lss[2] + lss[3];
        float mean = S * (1.f / 32768.f);
        float var  = SS * (1.f / 32768.f) - mean * mean;
        stats[bg * 2]     = mean;
        stats[bg * 2 + 1] = rsqrtf(var + 1e-5f);
    }
}

// ---------------------------------------------------------------------------
// Transpose + fp32->bf16: in [C][NPIX] per batch -> out [NPIX][C] bf16.
template<int C, int NPIX>
__global__ __launch_bounds__(256) void tconv_kernel(const float* __restrict__ in,
                                                    ushort* __restrict__ outp) {
    __shared__ ushort tile[64][68];
    int b = blockIdx.z, c0 = blockIdx.y * 64, n0 = blockIdx.x * 64;
    const float* ip = in + (size_t)b * C * NPIX;
    ushort* op = outp + (size_t)b * NPIX * C;
    int t = threadIdx.x;
    #pragma unroll
    for (int j = 0; j < 4; ++j) {
        int e = t + 256 * j;
        int cc = e >> 4, q = e & 15;
        float4 v = *(const float4*)&ip[(size_t)(c0 + cc) * NPIX + n0 + q * 4];
        ushort4 u;
        u.x = f2bf(v.x); u.y = f2bf(v.y); u.z = f2bf(v.z); u.w = f2bf(v.w);
        *(ushort4*)&tile[cc][q * 4] = u;
    }
    __syncthreads();
    #pragma unroll
    for (int j = 0; j < 4; ++j) {
        int e = t + 256 * j;
        int nn = e >> 4, q = e & 15;
        ushort4 u;
        u.x = tile[q*4+0][nn]; u.y = tile[q*4+1][nn];
        u.z = tile[q*4+2][nn]; u.w = tile[q*4+3][nn];
        *(ushort4*)&op[(size_t)(n0 + nn) * C + c0 + q * 4] = u;
    }
}

__global__ void cvtw_kernel(const float* __restrict__ w, ushort* __restrict__ o, int n) {
    int i = blockIdx.x * 256 + threadIdx.x;
    if (i < n) o[i] = f2bf(w[i]);
}

// ---------------------------------------------------------------------------
// NT-GEMM bf16 MFMA: C[b][r][c] = sum_k A[b][r][k]*B[b][c][k] + bias[b][r]
// A: [256][K] bf16 row-major, B: [N][K] bf16 row-major. 128x128 tile, BK=64,
// 4 waves (2x2 of 64x64), global_load_lds 16B with XOR-swizzled source.
template<int K, int N, bool OUTF32>
__global__ __launch_bounds__(256) void nt_gemm(const ushort* __restrict__ Amat, long long strideA,
                                               const ushort* __restrict__ Bmat, long long strideB,
                                               const float* __restrict__ biasv, int strideBias,
                                               void* __restrict__ Cmat, long long strideC) {
    __shared__ ushort lA[128 * 64];
    __shared__ ushort lB[128 * 64];
    int b = blockIdx.z;
    int col0 = blockIdx.x * 128, row0 = blockIdx.y * 128;
    int t = threadIdx.x;
    int l = t & 63, wid = t >> 6;
    int wr = wid >> 1, wc = wid & 1;
    int lr = l & 15, lg = l >> 4;
    const ushort* Ab = Amat + (size_t)b * strideA + (size_t)row0 * K;
    const ushort* Bb = Bmat + (size_t)b * strideB + (size_t)col0 * K;
    f32x4 acc[4][4] = {};
    for (int k0 = 0; k0 < K; k0 += 64) {
        #pragma unroll
        for (int j = 0; j < 4; ++j) {
            int gi = j * 256 + t;
            int r = gi >> 3, g = (gi & 7) ^ (r & 7);   // pre-swizzled source granule
            gload16(Ab + (size_t)r * K + k0 + g * 8, (char*)lA + gi * 16);
        }
        #pragma unroll
        for (int j = 0; j < 4; ++j) {
            int gi = j * 256 + t;
            int r = gi >> 3, g = (gi & 7) ^ (r & 7);
            gload16(Bb + (size_t)r * K + k0 + g * 8, (char*)lB + gi * 16);
        }
        __syncthreads();
        #pragma unroll
        for (int ks = 0; ks < 2; ++ks) {
            bf16x8 av[4], bv[4];
            #pragma unroll
            for (int mi = 0; mi < 4; ++mi) {
                int ar = wr * 64 + mi * 16 + lr;
                int q = (ks * 4 + lg) ^ (ar & 7);       // swizzled read
                av[mi] = *(const bf16x8*)((const char*)lA + ar * 128 + q * 16);
            }
            #pragma unroll
            for (int ni = 0; ni < 4; ++ni) {
                int br = wc * 64 + ni * 16 + lr;
                int q = (ks * 4 + lg) ^ (br & 7);
                bv[ni] = *(const bf16x8*)((const char*)lB + br * 128 + q * 16);
            }
            #pragma unroll
            for (int mi = 0; mi < 4; ++mi)
                #pragma unroll
                for (int ni = 0; ni < 4; ++ni)
                    acc[mi][ni] = __builtin_amdgcn_mfma_f32_16x16x32_bf16(
                        av[mi], bv[ni], acc[mi][ni], 0, 0, 0);
        }
        __syncthreads();
    }
    const float* bp = biasv + (size_t)b * strideBias;
    int orow = row0 + wr * 64, ocol = col0 + wc * 64 + lr;
    #pragma unroll
    for (int mi = 0; mi < 4; ++mi) {
        int rb = orow + mi * 16 + lg * 4;
        float4 b4 = *(const float4*)&bp[rb];
        float bvr[4] = {b4.x, b4.y, b4.z, b4.w};
        #pragma unroll
        for (int ni = 0; ni < 4; ++ni) {
            int cc = ocol + ni * 16;
            #pragma unroll
            for (int r = 0; r < 4; ++r) {
                float v = acc[mi][ni][r] + bvr[r];
                if constexpr (OUTF32)
                    ((float*)Cmat + (size_t)b * strideC)[(size_t)(rb + r) * N + cc] = v;
                else
                    ((ushort*)Cmat + (size_t)b * strideC)[(size_t)(rb + r) * N + cc] = f2bf(v);
            }
        }
    }
}

// ---------------------------------------------------------------------------
// K3: per (b,h): softmax over k rows (1024), context[d,e] = sum_n p[d,n] v[e,n]
__global__ __launch_bounds__(256) void ctx_kernel(const ushort* __restrict__ kv,
                                                  float* __restrict__ ctx) {
    int b = blockIdx.x >> 2, h = blockIdx.x & 3;
    const ushort* kp = kv + ((size_t)b * 256 + h * 32) * 1024;
    const ushort* vp = kv + ((size_t)b * 256 + 128 + h * 32) * 1024;
    __shared__ float pl[32][66], vl[32][66];
    int t = threadIdx.x;
    int d = t >> 3, lq = t & 7;
    const ushort* krow = kp + d * 1024 + lq * 128;
    float m = -INFINITY;
    #pragma unroll
    for (int jj = 0; jj < 16; ++jj) {
        uint4 raw = *(const uint4*)(krow + jj * 8);
        m = fmaxf(m, fmaxf(fmaxf(fmaxf(bflo(raw.x), bfhi(raw.x)), fmaxf(bflo(raw.y), bfhi(raw.y))),
                           fmaxf(fmaxf(bflo(raw.z), bfhi(raw.z)), fmaxf(bflo(raw.w), bfhi(raw.w)))));
    }
    m = fmaxf(m, __shfl_xor(m, 1, 64));
    m = fmaxf(m, __shfl_xor(m, 2, 64));
    m = fmaxf(m, __shfl_xor(m, 4, 64));
    float s = 0.f;
    #pragma unroll
    for (int jj = 0; jj < 16; ++jj) {
        uint4 raw = *(const uint4*)(krow + jj * 8);
        s += __expf(bflo(raw.x) - m) + __expf(bfhi(raw.x) - m)
           + __expf(bflo(raw.y) - m) + __expf(bfhi(raw.y) - m)
           + __expf(bflo(raw.z) - m) + __expf(bfhi(raw.z) - m)
           + __expf(bflo(raw.w) - m) + __expf(bfhi(raw.w) - m);
    }
    s += __shfl_xor(s, 1, 64);
    s += __shfl_xor(s, 2, 64);
    s += __shfl_xor(s, 4, 64);
    float inv = 1.f / s;

    float acc[4] = {0.f, 0.f, 0.f, 0.f};
    int dd[4], ee[4];
    #pragma unroll
    for (int i = 0; i < 4; ++i) {
        int idx = t + 256 * i;
        dd[i] = idx >> 5;
        ee[i] = idx & 31;
    }
    for (int n0 = 0; n0 < 1024; n0 += 64) {
        __syncthreads();
        {
            int r = d, nn = lq * 8;
            uint4 kraw = *(const uint4*)(kp + r * 1024 + n0 + nn);
            uint4 vraw = *(const uint4*)(vp + r * 1024 + n0 + nn);
            pl[r][nn + 0] = __expf(bflo(kraw.x) - m) * inv;
            pl[r][nn + 1] = __expf(bfhi(kraw.x) - m) * inv;
            pl[r][nn + 2] = __expf(bflo(kraw.y) - m) * inv;
            pl[r][nn + 3] = __expf(bfhi(kraw.y) - m) * inv;
            pl[r][nn + 4] = __expf(bflo(kraw.z) - m) * inv;
            pl[r][nn + 5] = __expf(bfhi(kraw.z) - m) * inv;
            pl[r][nn + 6] = __expf(bflo(kraw.w) - m) * inv;
            pl[r][nn + 7] = __expf(bfhi(kraw.w) - m) * inv;
            vl[r][nn + 0] = bflo(vraw.x); vl[r][nn + 1] = bfhi(vraw.x);
            vl[r][nn + 2] = bflo(vraw.y); vl[r][nn + 3] = bfhi(vraw.y);
            vl[r][nn + 4] = bflo(vraw.z); vl[r][nn + 5] = bfhi(vraw.z);
            vl[r][nn + 6] = bflo(vraw.w); vl[r][nn + 7] = bfhi(vraw.w);
        }
        __syncthreads();
        #pragma unroll 8
        for (int nn = 0; nn < 64; ++nn) {
            #pragma unroll
            for (int i = 0; i < 4; ++i)
                acc[i] += pl[dd[i]][nn] * vl[ee[i]][nn];
        }
    }
    #pragma unroll
    for (int i = 0; i < 4; ++i)
        ctx[((size_t)blockIdx.x * 32 + dd[i]) * 32 + ee[i]] = acc[i];
}

// ---------------------------------------------------------------------------
// K4a: M[b][o][hd] = sum_e w_out[o, h*32+e] * ctx[b,h,d,e], hd = h*32+d
__global__ __launch_bounds__(256) void m_kernel(const float* __restrict__ w_out,
                                                const float* __restrict__ ctx,
                                                float* __restrict__ M) {
    int b   = blockIdx.x >> 7;
    int idx = (blockIdx.x & 127) * 256 + threadIdx.x;
    int o = idx >> 7, hd = idx & 127;
    int h = hd >> 5, d = hd & 31;
    const float* cp = ctx + (((size_t)b * 4 + h) * 32 + d) * 32;
    const float* wp = w_out + o * 128 + h * 32;
    float acc = 0.f;
    #pragma unroll
    for (int e = 0; e < 32; ++e) acc += wp[e] * cp[e];
    M[((size_t)b * 256 + o) * 128 + hd] = acc;
}

// K4b: per (b, 16 o's): A16[b,o,c] = bf16(wt*s), bias[b,o] = sum_c wt*t + M.b_q + b_out
__global__ __launch_bounds__(256) void a_kernel(const float* __restrict__ M,
                                                const float* __restrict__ w_q,
                                                const float* __restrict__ b_q,
                                                const float* __restrict__ stats,
                                                const float* __restrict__ gn_w,
                                                const float* __restrict__ gn_b,
                                                const float* __restrict__ b_out,
                                                ushort* __restrict__ A16,
                                                float* __restrict__ biasb) {
    __shared__ float ml[16][128];
    __shared__ float cbuf[256][17];
    __shared__ float pbuf[16][17];
    int b = blockIdx.x >> 4, ot = (blockIdx.x & 15) << 4;
    int t = threadIdx.x;
    #pragma unroll
    for (int j = 0; j < 8; ++j) {
        int e = t + 256 * j;
        ml[e >> 7][e & 127] = M[((size_t)b * 256 + ot) * 128 + e];
    }
    __syncthreads();
    int c = t, g = c >> 3;
    float mu   = stats[(b * 32 + g) * 2];
    float rstd = stats[(b * 32 + g) * 2 + 1];
    float sc = rstd * gn_w[c];
    float tc = gn_b[c] - mu * sc;
    float wt[16];
    #pragma unroll
    for (int o = 0; o < 16; ++o) wt[o] = 0.f;
    for (int hd = 0; hd < 128; ++hd) {
        float wq = w_q[hd * 256 + c];
        #pragma unroll
        for (int o = 0; o < 16; ++o) wt[o] += ml[o][hd] * wq;
    }
    ushort* Abp = A16 + ((size_t)b * 256 + ot) * 256 + c;
    #pragma unroll
    for (int o = 0; o < 16; ++o) {
        Abp[(size_t)o * 256] = f2bf(wt[o] * sc);
        cbuf[c][o] = wt[o] * tc;
    }
    __syncthreads();
    {
        int o = t >> 4, seg = t & 15;
        float p = 0.f;
        #pragma unroll
        for (int i = 0; i < 16; ++i) p += cbuf[seg * 16 + i][o];
        pbuf[o][seg] = p;
    }
    __syncthreads();
    if (t < 16) {
        int o = t;
        float sum = 0.f;
        #pragma unroll
        for (int s2 = 0; s2 < 16; ++s2) sum += pbuf[o][s2];
        float md = 0.f;
        #pragma unroll 8
        for (int hd = 0; hd < 128; ++hd) md += ml[o][hd] * b_q[hd];
        biasb[(size_t)b * 256 + ot + o] = sum + md + b_out[ot + o];
    }
}

extern "C" void kernel_launch(void* const* d_in, const int* in_sizes, int n_in,
                              void* d_out, int out_size, void* d_ws, size_t ws_size,
                              hipStream_t stream) {
    const float* x     = (const float*)d_in[0];
    const float* cond  = (const float*)d_in[1];
    const float* gn_w  = (const float*)d_in[2];
    const float* gn_b  = (const float*)d_in[3];
    const float* w_q   = (const float*)d_in[4];
    const float* b_q   = (const float*)d_in[5];
    const float* w_kv  = (const float*)d_in[6];
    const float* b_kv  = (const float*)d_in[7];
    const float* w_out = (const float*)d_in[8];
    const float* b_out = (const float*)d_in[9];
    float* out = (float*)d_out;

    float* f     = (float*)d_ws;
    float* stats = f;                       // 1024
    float* biasb = f + 1024;                // 4096
    float* ctx   = f + 5120;                // 65536
    float* M     = f + 70656;               // 524288
    ushort* u    = (ushort*)(f + 594944);
    ushort* wkv16 = u;                      // 131072
    ushort* kv16  = u + 131072;             // 4194304
    ushort* A16   = u + 4325376;            // 1048576
    ushort* xT    = u + 5373952;            // 16777216
    ushort* condT = u + 22151168;           // 8388608
    // total ~63.5 MB

    gn_stats_kernel<<<512, 256, 0, stream>>>(x, stats);
    tconv_kernel<256, 4096><<<dim3(64, 4, 16), 256, 0, stream>>>(x, xT);
    tconv_kernel<512, 1024><<<dim3(16, 8, 16), 256, 0, stream>>>(cond, condT);
    cvtw_kernel<<<512, 256, 0, stream>>>(w_kv, wkv16, 131072);
    nt_gemm<512, 1024, false><<<dim3(8, 2, 16), 256, 0, stream>>>(
        wkv16, 0, condT, (long long)512 * 1024, b_kv, 0, kv16, (long long)256 * 1024);
    ctx_kernel<<<64, 256, 0, stream>>>(kv16, ctx);
    m_kernel<<<2048, 256, 0, stream>>>(w_out, ctx, M);
    a_kernel<<<256, 256, 0, stream>>>(M, w_q, b_q, stats, gn_w, gn_b, b_out, A16, biasb);
    nt_gemm<256, 4096, true><<<dim3(32, 2, 16), 256, 0, stream>>>(
        A16, 65536, xT, (long long)4096 * 256, biasb, 256, out, (long long)256 * 4096);
}

// Round 4
// 103.790 us; speedup vs baseline: 3.7844x; 1.3847x over previous
//
#include <hip/hip_runtime.h>
#include <hip/hip_bf16.h>

typedef __attribute__((ext_vector_type(8))) short bf16x8;
typedef __attribute__((ext_vector_type(4))) float f32x4;

__device__ __forceinline__ ushort f2bf(float f) {
    __hip_bfloat16 h = __float2bfloat16(f);
    return __builtin_bit_cast(ushort, h);
}
__device__ __forceinline__ float bflo(unsigned u) { return __uint_as_float(u << 16); }
__device__ __forceinline__ float bfhi(unsigned u) { return __uint_as_float(u & 0xffff0000u); }

__device__ __forceinline__ void unpack8(uint4 r, float* o) {
    o[0] = bflo(r.x); o[1] = bfhi(r.x); o[2] = bflo(r.y); o[3] = bfhi(r.y);
    o[4] = bflo(r.z); o[5] = bfhi(r.z); o[6] = bflo(r.w); o[7] = bfhi(r.w);
}

__device__ __forceinline__ void gload16(const void* g, void* l) {
    __builtin_amdgcn_global_load_lds(
        (const __attribute__((address_space(1))) unsigned*)g,
        (__attribute__((address_space(3))) unsigned*)l,
        16, 0, 0);
}

// ---------------------------------------------------------------------------
// Transpose + fp32->bf16: in [C][NPIX] per batch -> out [NPIX][C] bf16.
// STATS: also accumulate per-(b,group) sum / sumsq into statacc via atomics.
template<int C, int NPIX, bool STATS>
__global__ __launch_bounds__(256) void tconv_kernel(const float* __restrict__ in,
                                                    ushort* __restrict__ outp,
                                                    float* __restrict__ statacc) {
    __shared__ ushort tile[64][68];
    __shared__ float gacc[8][2];
    int b = blockIdx.z, c0 = blockIdx.y * 64, n0 = blockIdx.x * 64;
    const float* ip = in + (size_t)b * C * NPIX;
    ushort* op = outp + (size_t)b * NPIX * C;
    int t = threadIdx.x;
    if (STATS) {
        if (t < 16) gacc[t >> 1][t & 1] = 0.f;
        __syncthreads();
    }
    float sj[4], ssj[4];
    #pragma unroll
    for (int j = 0; j < 4; ++j) {
        int e = t + 256 * j;
        int cc = e >> 4, q = e & 15;
        float4 v = *(const float4*)&ip[(size_t)(c0 + cc) * NPIX + n0 + q * 4];
        ushort4 u;
        u.x = f2bf(v.x); u.y = f2bf(v.y); u.z = f2bf(v.z); u.w = f2bf(v.w);
        *(ushort4*)&tile[cc][q * 4] = u;
        if (STATS) {
            sj[j]  = v.x + v.y + v.z + v.w;
            ssj[j] = v.x*v.x + v.y*v.y + v.z*v.z + v.w*v.w;
        }
    }
    if (STATS) {
        #pragma unroll
        for (int j = 0; j < 4; ++j) {
            #pragma unroll
            for (int off = 1; off < 16; off <<= 1) {
                sj[j]  += __shfl_xor(sj[j], off, 64);
                ssj[j] += __shfl_xor(ssj[j], off, 64);
            }
        }
        if ((t & 15) == 0) {
            #pragma unroll
            for (int j = 0; j < 4; ++j) {
                int cc = (t >> 4) + 16 * j;
                atomicAdd(&gacc[cc >> 3][0], sj[j]);
                atomicAdd(&gacc[cc >> 3][1], ssj[j]);
            }
        }
    }
    __syncthreads();
    #pragma unroll
    for (int j = 0; j < 4; ++j) {
        int e = t + 256 * j;
        int nn = e >> 4, q = e & 15;
        ushort4 u;
        u.x = tile[q*4+0][nn]; u.y = tile[q*4+1][nn];
        u.z = tile[q*4+2][nn]; u.w = tile[q*4+3][nn];
        *(ushort4*)&op[(size_t)(n0 + nn) * C + c0 + q * 4] = u;
    }
    if (STATS && t < 8) {
        int g = b * 32 + (c0 >> 3) + t;
        atomicAdd(&statacc[g * 2],     gacc[t][0]);
        atomicAdd(&statacc[g * 2 + 1], gacc[t][1]);
    }
}

__global__ void cvtw_kernel(const float* __restrict__ w, ushort* __restrict__ o, int n) {
    int i = blockIdx.x * 256 + threadIdx.x;
    if (i < n) o[i] = f2bf(w[i]);
}

// ---------------------------------------------------------------------------
// NT-GEMM bf16 MFMA: C[b][r][c] = sum_k A[b][r][k]*B[b][c][k] + bias[b][r]
template<int K, int N, bool OUTF32>
__global__ __launch_bounds__(256) void nt_gemm(const ushort* __restrict__ Amat, long long strideA,
                                               const ushort* __restrict__ Bmat, long long strideB,
                                               const float* __restrict__ biasv, int strideBias,
                                               void* __restrict__ Cmat, long long strideC) {
    __shared__ ushort lA[128 * 64];
    __shared__ ushort lB[128 * 64];
    int b = blockIdx.z;
    int col0 = blockIdx.x * 128, row0 = blockIdx.y * 128;
    int t = threadIdx.x;
    int l = t & 63, wid = t >> 6;
    int wr = wid >> 1, wc = wid & 1;
    int lr = l & 15, lg = l >> 4;
    const ushort* Ab = Amat + (size_t)b * strideA + (size_t)row0 * K;
    const ushort* Bb = Bmat + (size_t)b * strideB + (size_t)col0 * K;
    f32x4 acc[4][4] = {};
    for (int k0 = 0; k0 < K; k0 += 64) {
        #pragma unroll
        for (int j = 0; j < 4; ++j) {
            int gi = j * 256 + t;
            int r = gi >> 3, g = (gi & 7) ^ (r & 7);
            gload16(Ab + (size_t)r * K + k0 + g * 8, (char*)lA + gi * 16);
        }
        #pragma unroll
        for (int j = 0; j < 4; ++j) {
            int gi = j * 256 + t;
            int r = gi >> 3, g = (gi & 7) ^ (r & 7);
            gload16(Bb + (size_t)r * K + k0 + g * 8, (char*)lB + gi * 16);
        }
        __syncthreads();
        #pragma unroll
        for (int ks = 0; ks < 2; ++ks) {
            bf16x8 av[4], bv[4];
            #pragma unroll
            for (int mi = 0; mi < 4; ++mi) {
                int ar = wr * 64 + mi * 16 + lr;
                int q = (ks * 4 + lg) ^ (ar & 7);
                av[mi] = *(const bf16x8*)((const char*)lA + ar * 128 + q * 16);
            }
            #pragma unroll
            for (int ni = 0; ni < 4; ++ni) {
                int br = wc * 64 + ni * 16 + lr;
                int q = (ks * 4 + lg) ^ (br & 7);
                bv[ni] = *(const bf16x8*)((const char*)lB + br * 128 + q * 16);
            }
            #pragma unroll
            for (int mi = 0; mi < 4; ++mi)
                #pragma unroll
                for (int ni = 0; ni < 4; ++ni)
                    acc[mi][ni] = __builtin_amdgcn_mfma_f32_16x16x32_bf16(
                        av[mi], bv[ni], acc[mi][ni], 0, 0, 0);
        }
        __syncthreads();
    }
    const float* bp = biasv + (size_t)b * strideBias;
    int orow = row0 + wr * 64, ocol = col0 + wc * 64 + lr;
    #pragma unroll
    for (int mi = 0; mi < 4; ++mi) {
        int rb = orow + mi * 16 + lg * 4;
        float4 b4 = *(const float4*)&bp[rb];
        float bvr[4] = {b4.x, b4.y, b4.z, b4.w};
        #pragma unroll
        for (int ni = 0; ni < 4; ++ni) {
            int cc = ocol + ni * 16;
            #pragma unroll
            for (int r = 0; r < 4; ++r) {
                float v = acc[mi][ni][r] + bvr[r];
                if constexpr (OUTF32)
                    ((float*)Cmat + (size_t)b * strideC)[(size_t)(rb + r) * N + cc] = v;
                else
                    ((ushort*)Cmat + (size_t)b * strideC)[(size_t)(rb + r) * N + cc] = f2bf(v);
            }
        }
    }
}

// ---------------------------------------------------------------------------
// Softmax stats per k-row: m, 1/sum. 2048 rows, grid 256 x 256 threads.
__global__ __launch_bounds__(256) void ctx_stats_kernel(const ushort* __restrict__ kv,
                                                        float* __restrict__ smstats) {
    int bh = blockIdx.x >> 2, rg = blockIdx.x & 3;
    int b = bh >> 2, h = bh & 3;
    int lr = threadIdx.x >> 5, c = threadIdx.x & 31;
    int row = rg * 8 + lr;
    const ushort* rp = kv + ((size_t)b * 256 + h * 32 + row) * 1024 + c * 32;
    float v[32];
    #pragma unroll
    for (int j = 0; j < 4; ++j) unpack8(((const uint4*)rp)[j], v + j * 8);
    float m = v[0];
    #pragma unroll
    for (int i = 1; i < 32; ++i) m = fmaxf(m, v[i]);
    #pragma unroll
    for (int off = 1; off < 32; off <<= 1) m = fmaxf(m, __shfl_xor(m, off, 64));
    float s = 0.f;
    #pragma unroll
    for (int i = 0; i < 32; ++i) s += __expf(v[i] - m);
    #pragma unroll
    for (int off = 1; off < 32; off <<= 1) s += __shfl_xor(s, off, 64);
    if (c == 0) {
        int gr = bh * 32 + row;
        smstats[gr * 2]     = m;
        smstats[gr * 2 + 1] = 1.f / s;
    }
}

// ---------------------------------------------------------------------------
// Partial context: grid (8 nchunks, 64 bh); 32x32 outer-product over 128 n.
__global__ __launch_bounds__(256) void ctx_partial_kernel(const ushort* __restrict__ kv,
                                                          const float* __restrict__ smstats,
                                                          float* __restrict__ ctx) {
    int bh = blockIdx.y, b = bh >> 2, h = bh & 3;
    int n0 = blockIdx.x * 128;
    __shared__ float pl[32][129], vl[32][129];
    int t = threadIdx.x;
    int r = t >> 3, cs = (t & 7) * 16;
    const ushort* kp = kv + ((size_t)b * 256 + h * 32 + r) * 1024 + n0 + cs;
    const ushort* vp = kv + ((size_t)b * 256 + 128 + h * 32 + r) * 1024 + n0 + cs;
    float m = smstats[(bh * 32 + r) * 2], inv = smstats[(bh * 32 + r) * 2 + 1];
    float kvals[16], vvals[16];
    unpack8(((const uint4*)kp)[0], kvals);
    unpack8(((const uint4*)kp)[1], kvals + 8);
    unpack8(((const uint4*)vp)[0], vvals);
    unpack8(((const uint4*)vp)[1], vvals + 8);
    #pragma unroll
    for (int i = 0; i < 16; ++i) {
        pl[r][cs + i] = __expf(kvals[i] - m) * inv;
        vl[r][cs + i] = vvals[i];
    }
    __syncthreads();
    int d0 = t >> 5, e0 = t & 31;
    float acc[4] = {0.f, 0.f, 0.f, 0.f};
    #pragma unroll 8
    for (int nn = 0; nn < 128; ++nn) {
        float vv = vl[e0][nn];
        #pragma unroll
        for (int i = 0; i < 4; ++i)
            acc[i] += pl[d0 + 8 * i][nn] * vv;
    }
    #pragma unroll
    for (int i = 0; i < 4; ++i)
        atomicAdd(&ctx[((size_t)bh * 32 + d0 + 8 * i) * 32 + e0], acc[i]);
}

// ---------------------------------------------------------------------------
// A-fold: per (b, 16 o's): M = w_out@ctx^T in LDS, then
// A16[b,o,c] = bf16(wt*s), biasb[b,o] = sum_c wt*t + M.b_q + b_out
__global__ __launch_bounds__(256) void a_kernel(const float* __restrict__ ctx,
                                                const float* __restrict__ w_out,
                                                const float* __restrict__ w_q,
                                                const float* __restrict__ b_q,
                                                const float* __restrict__ statacc,
                                                const float* __restrict__ gn_w,
                                                const float* __restrict__ gn_b,
                                                const float* __restrict__ b_out,
                                                ushort* __restrict__ A16,
                                                float* __restrict__ biasb) {
    __shared__ float ctxl[4][32][33];
    __shared__ float wol[16][128];
    __shared__ float ml[16][128];
    __shared__ float cbuf[256][17];
    __shared__ float pbuf[16][17];
    int b = blockIdx.x >> 4, ot = (blockIdx.x & 15) << 4;
    int t = threadIdx.x;
    #pragma unroll
    for (int j = 0; j < 16; ++j) {
        int e = t + 256 * j;            // 0..4095
        ctxl[e >> 10][(e >> 5) & 31][e & 31] = ctx[(size_t)b * 4096 + e];
    }
    #pragma unroll
    for (int j = 0; j < 8; ++j) {
        int e = t + 256 * j;            // 0..2047
        wol[e >> 7][e & 127] = w_out[(ot + (e >> 7)) * 128 + (e & 127)];
    }
    __syncthreads();
    #pragma unroll
    for (int j = 0; j < 8; ++j) {
        int e = t + 256 * j;
        int o = e >> 7, hd = e & 127, h = hd >> 5, d = hd & 31;
        float acc = 0.f;
        #pragma unroll
        for (int ee = 0; ee < 32; ++ee) acc += wol[o][h * 32 + ee] * ctxl[h][d][ee];
        ml[o][hd] = acc;
    }
    __syncthreads();
    int c = t, g = c >> 3;
    float a0 = statacc[(b * 32 + g) * 2], a1 = statacc[(b * 32 + g) * 2 + 1];
    float mu  = a0 * (1.f / 32768.f);
    float var = a1 * (1.f / 32768.f) - mu * mu;
    float sc = rsqrtf(var + 1e-5f) * gn_w[c];
    float tc = gn_b[c] - mu * sc;
    float wt[16];
    #pragma unroll
    for (int o = 0; o < 16; ++o) wt[o] = 0.f;
    for (int hd = 0; hd < 128; ++hd) {
        float wq = w_q[hd * 256 + c];
        #pragma unroll
        for (int o = 0; o < 16; ++o) wt[o] += ml[o][hd] * wq;
    }
    ushort* Abp = A16 + ((size_t)b * 256 + ot) * 256 + c;
    #pragma unroll
    for (int o = 0; o < 16; ++o) {
        Abp[(size_t)o * 256] = f2bf(wt[o] * sc);
        cbuf[c][o] = wt[o] * tc;
    }
    __syncthreads();
    {
        int o = t >> 4, seg = t & 15;
        float p = 0.f;
        #pragma unroll
        for (int i = 0; i < 16; ++i) p += cbuf[seg * 16 + i][o];
        pbuf[o][seg] = p;
    }
    __syncthreads();
    if (t < 16) {
        int o = t;
        float sum = 0.f;
        #pragma unroll
        for (int s2 = 0; s2 < 16; ++s2) sum += pbuf[o][s2];
        float md = 0.f;
        #pragma unroll 8
        for (int hd = 0; hd < 128; ++hd) md += ml[o][hd] * b_q[hd];
        biasb[(size_t)b * 256 + ot + o] = sum + md + b_out[ot + o];
    }
}

extern "C" void kernel_launch(void* const* d_in, const int* in_sizes, int n_in,
                              void* d_out, int out_size, void* d_ws, size_t ws_size,
                              hipStream_t stream) {
    const float* x     = (const float*)d_in[0];
    const float* cond  = (const float*)d_in[1];
    const float* gn_w  = (const float*)d_in[2];
    const float* gn_b  = (const float*)d_in[3];
    const float* w_q   = (const float*)d_in[4];
    const float* b_q   = (const float*)d_in[5];
    const float* w_kv  = (const float*)d_in[6];
    const float* b_kv  = (const float*)d_in[7];
    const float* w_out = (const float*)d_in[8];
    const float* b_out = (const float*)d_in[9];
    float* out = (float*)d_out;

    float* f       = (float*)d_ws;
    float* statacc = f;                     // 1024
    float* biasb   = f + 1024;              // 4096
    float* ctx     = f + 5120;              // 65536
    float* smstats = f + 70656;             // 4096
    ushort* u      = (ushort*)(f + 74752);
    ushort* wkv16  = u;                     // 131072
    ushort* kv16   = u + 131072;            // 4194304
    ushort* A16    = u + 4325376;           // 1048576
    ushort* xT     = u + 5373952;           // 16777216
    ushort* condT  = u + 22151168;          // 8388608

    hipMemsetAsync(statacc, 0, 1024 * sizeof(float), stream);
    hipMemsetAsync(ctx, 0, 65536 * sizeof(float), stream);
    tconv_kernel<256, 4096, true><<<dim3(64, 4, 16), 256, 0, stream>>>(x, xT, statacc);
    tconv_kernel<512, 1024, false><<<dim3(16, 8, 16), 256, 0, stream>>>(cond, condT, nullptr);
    cvtw_kernel<<<512, 256, 0, stream>>>(w_kv, wkv16, 131072);
    nt_gemm<512, 1024, false><<<dim3(8, 2, 16), 256, 0, stream>>>(
        wkv16, 0, condT, (long long)512 * 1024, b_kv, 0, kv16, (long long)256 * 1024);
    ctx_stats_kernel<<<256, 256, 0, stream>>>(kv16, smstats);
    ctx_partial_kernel<<<dim3(8, 64), 256, 0, stream>>>(kv16, smstats, ctx);
    a_kernel<<<256, 256, 0, stream>>>(ctx, w_out, w_q, b_q, statacc, gn_w, gn_b, b_out, A16, biasb);
    nt_gemm<256, 4096, true><<<dim3(32, 2, 16), 256, 0, stream>>>(
        A16, 65536, xT, (long long)4096 * 256, biasb, 256, out, (long long)256 * 4096);
}

// Round 5
// 99.689 us; speedup vs baseline: 3.9401x; 1.0411x over previous
//
#include <hip/hip_runtime.h>
#include <hip/hip_bf16.h>

typedef __attribute__((ext_vector_type(8))) short bf16x8;
typedef __attribute__((ext_vector_type(4))) float f32x4;

__device__ __forceinline__ ushort f2bf(float f) {
    __hip_bfloat16 h = __float2bfloat16(f);
    return __builtin_bit_cast(ushort, h);
}
__device__ __forceinline__ float bflo(unsigned u) { return __uint_as_float(u << 16); }
__device__ __forceinline__ float bfhi(unsigned u) { return __uint_as_float(u & 0xffff0000u); }

__device__ __forceinline__ void unpack8(uint4 r, float* o) {
    o[0] = bflo(r.x); o[1] = bfhi(r.x); o[2] = bflo(r.y); o[3] = bfhi(r.y);
    o[4] = bflo(r.z); o[5] = bfhi(r.z); o[6] = bflo(r.w); o[7] = bfhi(r.w);
}

__device__ __forceinline__ void gload16(const void* g, void* l) {
    __builtin_amdgcn_global_load_lds(
        (const __attribute__((address_space(1))) unsigned*)g,
        (__attribute__((address_space(3))) unsigned*)l,
        16, 0, 0);
}

// ---------------------------------------------------------------------------
// Transpose + fp32->bf16: in [C][NPIX] per batch -> out [NPIX][C] bf16.
// STATS: also accumulate per-(b,group) sum / sumsq into statacc via atomics.
template<int C, int NPIX, bool STATS>
__global__ __launch_bounds__(256) void tconv_kernel(const float* __restrict__ in,
                                                    ushort* __restrict__ outp,
                                                    float* __restrict__ statacc) {
    __shared__ ushort tile[64][68];
    __shared__ float gacc[8][2];
    int b = blockIdx.z, c0 = blockIdx.y * 64, n0 = blockIdx.x * 64;
    const float* ip = in + (size_t)b * C * NPIX;
    ushort* op = outp + (size_t)b * NPIX * C;
    int t = threadIdx.x;
    if (STATS) {
        if (t < 16) gacc[t >> 1][t & 1] = 0.f;
        __syncthreads();
    }
    float sj[4], ssj[4];
    #pragma unroll
    for (int j = 0; j < 4; ++j) {
        int e = t + 256 * j;
        int cc = e >> 4, q = e & 15;
        float4 v = *(const float4*)&ip[(size_t)(c0 + cc) * NPIX + n0 + q * 4];
        ushort4 u;
        u.x = f2bf(v.x); u.y = f2bf(v.y); u.z = f2bf(v.z); u.w = f2bf(v.w);
        *(ushort4*)&tile[cc][q * 4] = u;
        if (STATS) {
            sj[j]  = v.x + v.y + v.z + v.w;
            ssj[j] = v.x*v.x + v.y*v.y + v.z*v.z + v.w*v.w;
        }
    }
    if (STATS) {
        #pragma unroll
        for (int j = 0; j < 4; ++j) {
            #pragma unroll
            for (int off = 1; off < 16; off <<= 1) {
                sj[j]  += __shfl_xor(sj[j], off, 64);
                ssj[j] += __shfl_xor(ssj[j], off, 64);
            }
        }
        if ((t & 15) == 0) {
            #pragma unroll
            for (int j = 0; j < 4; ++j) {
                int cc = (t >> 4) + 16 * j;
                atomicAdd(&gacc[cc >> 3][0], sj[j]);
                atomicAdd(&gacc[cc >> 3][1], ssj[j]);
            }
        }
    }
    __syncthreads();
    #pragma unroll
    for (int j = 0; j < 4; ++j) {
        int e = t + 256 * j;
        int nn = e >> 4, q = e & 15;
        ushort4 u;
        u.x = tile[q*4+0][nn]; u.y = tile[q*4+1][nn];
        u.z = tile[q*4+2][nn]; u.w = tile[q*4+3][nn];
        *(ushort4*)&op[(size_t)(n0 + nn) * C + c0 + q * 4] = u;
    }
    if (STATS && t < 8) {
        int g = b * 32 + (c0 >> 3) + t;
        atomicAdd(&statacc[g * 2],     gacc[t][0]);
        atomicAdd(&statacc[g * 2 + 1], gacc[t][1]);
    }
}

// Also zeroes statacc (1024 floats) -- must be launched BEFORE tconv_x.
__global__ void cvtw_kernel(const float* __restrict__ w, ushort* __restrict__ o, int n,
                            float* __restrict__ statacc) {
    int i = blockIdx.x * 256 + threadIdx.x;
    if (i < 1024) statacc[i] = 0.f;
    if (i < n) o[i] = f2bf(w[i]);
}

// ---------------------------------------------------------------------------
// NT-GEMM bf16 MFMA: C[b][r][c] = sum_k A[b][r][k]*B[b][c][k] + bias[b][r]
template<int K, int N, bool OUTF32>
__global__ __launch_bounds__(256) void nt_gemm(const ushort* __restrict__ Amat, long long strideA,
                                               const ushort* __restrict__ Bmat, long long strideB,
                                               const float* __restrict__ biasv, int strideBias,
                                               void* __restrict__ Cmat, long long strideC) {
    __shared__ ushort lA[128 * 64];
    __shared__ ushort lB[128 * 64];
    int b = blockIdx.z;
    int col0 = blockIdx.x * 128, row0 = blockIdx.y * 128;
    int t = threadIdx.x;
    int l = t & 63, wid = t >> 6;
    int wr = wid >> 1, wc = wid & 1;
    int lr = l & 15, lg = l >> 4;
    const ushort* Ab = Amat + (size_t)b * strideA + (size_t)row0 * K;
    const ushort* Bb = Bmat + (size_t)b * strideB + (size_t)col0 * K;
    f32x4 acc[4][4] = {};
    for (int k0 = 0; k0 < K; k0 += 64) {
        #pragma unroll
        for (int j = 0; j < 4; ++j) {
            int gi = j * 256 + t;
            int r = gi >> 3, g = (gi & 7) ^ (r & 7);
            gload16(Ab + (size_t)r * K + k0 + g * 8, (char*)lA + gi * 16);
        }
        #pragma unroll
        for (int j = 0; j < 4; ++j) {
            int gi = j * 256 + t;
            int r = gi >> 3, g = (gi & 7) ^ (r & 7);
            gload16(Bb + (size_t)r * K + k0 + g * 8, (char*)lB + gi * 16);
        }
        __syncthreads();
        #pragma unroll
        for (int ks = 0; ks < 2; ++ks) {
            bf16x8 av[4], bv[4];
            #pragma unroll
            for (int mi = 0; mi < 4; ++mi) {
                int ar = wr * 64 + mi * 16 + lr;
                int q = (ks * 4 + lg) ^ (ar & 7);
                av[mi] = *(const bf16x8*)((const char*)lA + ar * 128 + q * 16);
            }
            #pragma unroll
            for (int ni = 0; ni < 4; ++ni) {
                int br = wc * 64 + ni * 16 + lr;
                int q = (ks * 4 + lg) ^ (br & 7);
                bv[ni] = *(const bf16x8*)((const char*)lB + br * 128 + q * 16);
            }
            #pragma unroll
            for (int mi = 0; mi < 4; ++mi)
                #pragma unroll
                for (int ni = 0; ni < 4; ++ni)
                    acc[mi][ni] = __builtin_amdgcn_mfma_f32_16x16x32_bf16(
                        av[mi], bv[ni], acc[mi][ni], 0, 0, 0);
        }
        __syncthreads();
    }
    const float* bp = biasv + (size_t)b * strideBias;
    int orow = row0 + wr * 64, ocol = col0 + wc * 64 + lr;
    #pragma unroll
    for (int mi = 0; mi < 4; ++mi) {
        int rb = orow + mi * 16 + lg * 4;
        float4 b4 = *(const float4*)&bp[rb];
        float bvr[4] = {b4.x, b4.y, b4.z, b4.w};
        #pragma unroll
        for (int ni = 0; ni < 4; ++ni) {
            int cc = ocol + ni * 16;
            #pragma unroll
            for (int r = 0; r < 4; ++r) {
                float v = acc[mi][ni][r] + bvr[r];
                if constexpr (OUTF32)
                    ((float*)Cmat + (size_t)b * strideC)[(size_t)(rb + r) * N + cc] = v;
                else
                    ((ushort*)Cmat + (size_t)b * strideC)[(size_t)(rb + r) * N + cc] = f2bf(v);
            }
        }
    }
}

// ---------------------------------------------------------------------------
// Softmax stats per k-row: m, 1/sum. 2048 rows, grid 256 x 256 threads.
// Also zeroes ctx (65536 floats) -- runs BEFORE ctx_partial's atomics.
__global__ __launch_bounds__(256) void ctx_stats_kernel(const ushort* __restrict__ kv,
                                                        float* __restrict__ smstats,
                                                        float* __restrict__ ctx) {
    ctx[blockIdx.x * 256 + threadIdx.x] = 0.f;
    int bh = blockIdx.x >> 2, rg = blockIdx.x & 3;
    int b = bh >> 2, h = bh & 3;
    int lr = threadIdx.x >> 5, c = threadIdx.x & 31;
    int row = rg * 8 + lr;
    const ushort* rp = kv + ((size_t)b * 256 + h * 32 + row) * 1024 + c * 32;
    float v[32];
    #pragma unroll
    for (int j = 0; j < 4; ++j) unpack8(((const uint4*)rp)[j], v + j * 8);
    float m = v[0];
    #pragma unroll
    for (int i = 1; i < 32; ++i) m = fmaxf(m, v[i]);
    #pragma unroll
    for (int off = 1; off < 32; off <<= 1) m = fmaxf(m, __shfl_xor(m, off, 64));
    float s = 0.f;
    #pragma unroll
    for (int i = 0; i < 32; ++i) s += __expf(v[i] - m);
    #pragma unroll
    for (int off = 1; off < 32; off <<= 1) s += __shfl_xor(s, off, 64);
    if (c == 0) {
        int gr = bh * 32 + row;
        smstats[gr * 2]     = m;
        smstats[gr * 2 + 1] = 1.f / s;
    }
}

// ---------------------------------------------------------------------------
// Partial context: grid (8 nchunks, 64 bh); 32x32 outer-product over 128 n.
__global__ __launch_bounds__(256) void ctx_partial_kernel(const ushort* __restrict__ kv,
                                                          const float* __restrict__ smstats,
                                                          float* __restrict__ ctx) {
    int bh = blockIdx.y, b = bh >> 2, h = bh & 3;
    int n0 = blockIdx.x * 128;
    __shared__ float pl[32][129], vl[32][129];
    int t = threadIdx.x;
    int r = t >> 3, cs = (t & 7) * 16;
    const ushort* kp = kv + ((size_t)b * 256 + h * 32 + r) * 1024 + n0 + cs;
    const ushort* vp = kv + ((size_t)b * 256 + 128 + h * 32 + r) * 1024 + n0 + cs;
    float m = smstats[(bh * 32 + r) * 2], inv = smstats[(bh * 32 + r) * 2 + 1];
    float kvals[16], vvals[16];
    unpack8(((const uint4*)kp)[0], kvals);
    unpack8(((const uint4*)kp)[1], kvals + 8);
    unpack8(((const uint4*)vp)[0], vvals);
    unpack8(((const uint4*)vp)[1], vvals + 8);
    #pragma unroll
    for (int i = 0; i < 16; ++i) {
        pl[r][cs + i] = __expf(kvals[i] - m) * inv;
        vl[r][cs + i] = vvals[i];
    }
    __syncthreads();
    int d0 = t >> 5, e0 = t & 31;
    float acc[4] = {0.f, 0.f, 0.f, 0.f};
    #pragma unroll 8
    for (int nn = 0; nn < 128; ++nn) {
        float vv = vl[e0][nn];
        #pragma unroll
        for (int i = 0; i < 4; ++i)
            acc[i] += pl[d0 + 8 * i][nn] * vv;
    }
    #pragma unroll
    for (int i = 0; i < 4; ++i)
        atomicAdd(&ctx[((size_t)bh * 32 + d0 + 8 * i) * 32 + e0], acc[i]);
}

// ---------------------------------------------------------------------------
// A-fold: per (b, 16 o's): M = w_out@ctx^T in LDS, then
// A16[b,o,c] = bf16(wt*s), biasb[b,o] = sum_c wt*t + M.b_q + b_out
__global__ __launch_bounds__(256) void a_kernel(const float* __restrict__ ctx,
                                                const float* __restrict__ w_out,
                                                const float* __restrict__ w_q,
                                                const float* __restrict__ b_q,
                                                const float* __restrict__ statacc,
                                                const float* __restrict__ gn_w,
                                                const float* __restrict__ gn_b,
                                                const float* __restrict__ b_out,
                                                ushort* __restrict__ A16,
                                                float* __restrict__ biasb) {
    __shared__ float ctxl[4][32][33];
    __shared__ float wol[16][128];
    __shared__ float ml[16][128];
    __shared__ float cbuf[256][17];
    __shared__ float pbuf[16][17];
    int b = blockIdx.x >> 4, ot = (blockIdx.x & 15) << 4;
    int t = threadIdx.x;
    #pragma unroll
    for (int j = 0; j < 16; ++j) {
        int e = t + 256 * j;            // 0..4095
        ctxl[e >> 10][(e >> 5) & 31][e & 31] = ctx[(size_t)b * 4096 + e];
    }
    #pragma unroll
    for (int j = 0; j < 8; ++j) {
        int e = t + 256 * j;            // 0..2047
        wol[e >> 7][e & 127] = w_out[(ot + (e >> 7)) * 128 + (e & 127)];
    }
    __syncthreads();
    #pragma unroll
    for (int j = 0; j < 8; ++j) {
        int e = t + 256 * j;
        int o = e >> 7, hd = e & 127, h = hd >> 5, d = hd & 31;
        float acc = 0.f;
        #pragma unroll
        for (int ee = 0; ee < 32; ++ee) acc += wol[o][h * 32 + ee] * ctxl[h][d][ee];
        ml[o][hd] = acc;
    }
    __syncthreads();
    int c = t, g = c >> 3;
    float a0 = statacc[(b * 32 + g) * 2], a1 = statacc[(b * 32 + g) * 2 + 1];
    float mu  = a0 * (1.f / 32768.f);
    float var = a1 * (1.f / 32768.f) - mu * mu;
    float sc = rsqrtf(var + 1e-5f) * gn_w[c];
    float tc = gn_b[c] - mu * sc;
    float wt[16];
    #pragma unroll
    for (int o = 0; o < 16; ++o) wt[o] = 0.f;
    for (int hd = 0; hd < 128; ++hd) {
        float wq = w_q[hd * 256 + c];
        #pragma unroll
        for (int o = 0; o < 16; ++o) wt[o] += ml[o][hd] * wq;
    }
    ushort* Abp = A16 + ((size_t)b * 256 + ot) * 256 + c;
    #pragma unroll
    for (int o = 0; o < 16; ++o) {
        Abp[(size_t)o * 256] = f2bf(wt[o] * sc);
        cbuf[c][o] = wt[o] * tc;
    }
    __syncthreads();
    {
        int o = t >> 4, seg = t & 15;
        float p = 0.f;
        #pragma unroll
        for (int i = 0; i < 16; ++i) p += cbuf[seg * 16 + i][o];
        pbuf[o][seg] = p;
    }
    __syncthreads();
    if (t < 16) {
        int o = t;
        float sum = 0.f;
        #pragma unroll
        for (int s2 = 0; s2 < 16; ++s2) sum += pbuf[o][s2];
        float md = 0.f;
        #pragma unroll 8
        for (int hd = 0; hd < 128; ++hd) md += ml[o][hd] * b_q[hd];
        biasb[(size_t)b * 256 + ot + o] = sum + md + b_out[ot + o];
    }
}

extern "C" void kernel_launch(void* const* d_in, const int* in_sizes, int n_in,
                              void* d_out, int out_size, void* d_ws, size_t ws_size,
                              hipStream_t stream) {
    const float* x     = (const float*)d_in[0];
    const float* cond  = (const float*)d_in[1];
    const float* gn_w  = (const float*)d_in[2];
    const float* gn_b  = (const float*)d_in[3];
    const float* w_q   = (const float*)d_in[4];
    const float* b_q   = (const float*)d_in[5];
    const float* w_kv  = (const float*)d_in[6];
    const float* b_kv  = (const float*)d_in[7];
    const float* w_out = (const float*)d_in[8];
    const float* b_out = (const float*)d_in[9];
    float* out = (float*)d_out;

    float* f       = (float*)d_ws;
    float* statacc = f;                     // 1024
    float* biasb   = f + 1024;              // 4096
    float* ctx     = f + 5120;              // 65536
    float* smstats = f + 70656;             // 4096
    ushort* u      = (ushort*)(f + 74752);
    ushort* wkv16  = u;                     // 131072
    ushort* kv16   = u + 131072;            // 4194304
    ushort* A16    = u + 4325376;           // 1048576
    ushort* xT     = u + 5373952;           // 16777216
    ushort* condT  = u + 22151168;          // 8388608

    // cvtw zeroes statacc; must precede tconv_x (stream order).
    cvtw_kernel<<<512, 256, 0, stream>>>(w_kv, wkv16, 131072, statacc);
    tconv_kernel<256, 4096, true><<<dim3(64, 4, 16), 256, 0, stream>>>(x, xT, statacc);
    tconv_kernel<512, 1024, false><<<dim3(16, 8, 16), 256, 0, stream>>>(cond, condT, nullptr);
    nt_gemm<512, 1024, false><<<dim3(8, 2, 16), 256, 0, stream>>>(
        wkv16, 0, condT, (long long)512 * 1024, b_kv, 0, kv16, (long long)256 * 1024);
    // ctx_stats zeroes ctx; must precede ctx_partial (stream order).
    ctx_stats_kernel<<<256, 256, 0, stream>>>(kv16, smstats, ctx);
    ctx_partial_kernel<<<dim3(8, 64), 256, 0, stream>>>(kv16, smstats, ctx);
    a_kernel<<<256, 256, 0, stream>>>(ctx, w_out, w_q, b_q, statacc, gn_w, gn_b, b_out, A16, biasb);
    nt_gemm<256, 4096, true><<<dim3(32, 2, 16), 256, 0, stream>>>(
        A16, 65536, xT, (long long)4096 * 256, biasb, 256, out, (long long)256 * 4096);
}

// Round 7
// 90.601 us; speedup vs baseline: 4.3353x; 1.1003x over previous
//
#include <hip/hip_runtime.h>
#include <hip/hip_bf16.h>

typedef __attribute__((ext_vector_type(8))) short bf16x8;
typedef __attribute__((ext_vector_type(4))) float f32x4;

__device__ __forceinline__ ushort f2bf(float f) {
    __hip_bfloat16 h = __float2bfloat16(f);
    return __builtin_bit_cast(ushort, h);
}
__device__ __forceinline__ float bflo(unsigned u) { return __uint_as_float(u << 16); }
__device__ __forceinline__ float bfhi(unsigned u) { return __uint_as_float(u & 0xffff0000u); }

__device__ __forceinline__ void unpack8(uint4 r, float* o) {
    o[0] = bflo(r.x); o[1] = bfhi(r.x); o[2] = bflo(r.y); o[3] = bfhi(r.y);
    o[4] = bflo(r.z); o[5] = bfhi(r.z); o[6] = bflo(r.w); o[7] = bfhi(r.w);
}

__device__ __forceinline__ void gload16(const void* g, void* l) {
    __builtin_amdgcn_global_load_lds(
        (const __attribute__((address_space(1))) unsigned*)g,
        (__attribute__((address_space(3))) unsigned*)l,
        16, 0, 0);
}

// ---------------------------------------------------------------------------
// L1: convert w_kv to bf16 AND zero the atomic accumulators
// (statacc 1024 | rowsum 2048 | ctx 65536 contiguous at f[0..68608)).
__global__ void cvtw_kernel(const float* __restrict__ w, ushort* __restrict__ o,
                            float* __restrict__ zbase) {
    int i = blockIdx.x * 256 + threadIdx.x;      // 0..131071
    if (i < 68608) zbase[i] = 0.f;
    o[i] = f2bf(w[i]);
}

// ---------------------------------------------------------------------------
// Transpose + fp32->bf16 body: in [C][NPIX] per batch -> out [NPIX][C] bf16.
template<int C, int NPIX, bool STATS>
__device__ __forceinline__ void tconv_body(const float* __restrict__ in,
                                           ushort* __restrict__ outp,
                                           float* __restrict__ statacc,
                                           int b, int c0, int n0) {
    __shared__ ushort tile[64][68];
    __shared__ float gacc[8][2];
    const float* ip = in + (size_t)b * C * NPIX;
    ushort* op = outp + (size_t)b * NPIX * C;
    int t = threadIdx.x;
    if (STATS) {
        if (t < 16) gacc[t >> 1][t & 1] = 0.f;
        __syncthreads();
    }
    float sj[4], ssj[4];
    #pragma unroll
    for (int j = 0; j < 4; ++j) {
        int e = t + 256 * j;
        int cc = e >> 4, q = e & 15;
        float4 v = *(const float4*)&ip[(size_t)(c0 + cc) * NPIX + n0 + q * 4];
        ushort4 u;
        u.x = f2bf(v.x); u.y = f2bf(v.y); u.z = f2bf(v.z); u.w = f2bf(v.w);
        *(ushort4*)&tile[cc][q * 4] = u;
        if (STATS) {
            sj[j]  = v.x + v.y + v.z + v.w;
            ssj[j] = v.x*v.x + v.y*v.y + v.z*v.z + v.w*v.w;
        }
    }
    if (STATS) {
        #pragma unroll
        for (int j = 0; j < 4; ++j) {
            #pragma unroll
            for (int off = 1; off < 16; off <<= 1) {
                sj[j]  += __shfl_xor(sj[j], off, 64);
                ssj[j] += __shfl_xor(ssj[j], off, 64);
            }
        }
        if ((t & 15) == 0) {
            #pragma unroll
            for (int j = 0; j < 4; ++j) {
                int cc = (t >> 4) + 16 * j;
                atomicAdd(&gacc[cc >> 3][0], sj[j]);
                atomicAdd(&gacc[cc >> 3][1], ssj[j]);
            }
        }
    }
    __syncthreads();
    #pragma unroll
    for (int j = 0; j < 4; ++j) {
        int e = t + 256 * j;
        int nn = e >> 4, q = e & 15;
        ushort4 u;
        u.x = tile[q*4+0][nn]; u.y = tile[q*4+1][nn];
        u.z = tile[q*4+2][nn]; u.w = tile[q*4+3][nn];
        *(ushort4*)&op[(size_t)(n0 + nn) * C + c0 + q * 4] = u;
    }
    if (STATS && t < 8) {
        int g = b * 32 + (c0 >> 3) + t;
        atomicAdd(&statacc[g * 2],     gacc[t][0]);
        atomicAdd(&statacc[g * 2 + 1], gacc[t][1]);
    }
}

// L2: merged transpose for x (with GN stats) and cond. 4096 + 2048 blocks.
__global__ __launch_bounds__(256) void tpose_kernel(const float* __restrict__ x,
                                                    const float* __restrict__ cond,
                                                    ushort* __restrict__ xT,
                                                    ushort* __restrict__ condT,
                                                    float* __restrict__ statacc) {
    int bid = blockIdx.x;
    if (bid < 4096) {
        int b = bid >> 8, rem = bid & 255;
        tconv_body<256, 4096, true>(x, xT, statacc, b, (rem >> 6) * 64, (rem & 63) * 64);
    } else {
        int id = bid - 4096;
        int b = id >> 7, rem = id & 127;
        tconv_body<512, 1024, false>(cond, condT, nullptr, b, (rem >> 4) * 64, (rem & 15) * 64);
    }
}

// ---------------------------------------------------------------------------
// NT-GEMM bf16 MFMA 128x128 tile: C[b][r][c] = sum_k A[b][r][k]*B[b][c][k] + bias[b][r]
template<int K, int N, bool OUTF32>
__global__ __launch_bounds__(256) void nt_gemm(const ushort* __restrict__ Amat, long long strideA,
                                               const ushort* __restrict__ Bmat, long long strideB,
                                               const float* __restrict__ biasv, int strideBias,
                                               void* __restrict__ Cmat, long long strideC) {
    __shared__ ushort lA[128 * 64];
    __shared__ ushort lB[128 * 64];
    int b = blockIdx.z;
    int col0 = blockIdx.x * 128, row0 = blockIdx.y * 128;
    int t = threadIdx.x;
    int l = t & 63, wid = t >> 6;
    int wr = wid >> 1, wc = wid & 1;
    int lr = l & 15, lg = l >> 4;
    const ushort* Ab = Amat + (size_t)b * strideA + (size_t)row0 * K;
    const ushort* Bb = Bmat + (size_t)b * strideB + (size_t)col0 * K;
    f32x4 acc[4][4] = {};
    for (int k0 = 0; k0 < K; k0 += 64) {
        #pragma unroll
        for (int j = 0; j < 4; ++j) {
            int gi = j * 256 + t;
            int r = gi >> 3, g = (gi & 7) ^ (r & 7);
            gload16(Ab + (size_t)r * K + k0 + g * 8, (char*)lA + gi * 16);
        }
        #pragma unroll
        for (int j = 0; j < 4; ++j) {
            int gi = j * 256 + t;
            int r = gi >> 3, g = (gi & 7) ^ (r & 7);
            gload16(Bb + (size_t)r * K + k0 + g * 8, (char*)lB + gi * 16);
        }
        __syncthreads();
        #pragma unroll
        for (int ks = 0; ks < 2; ++ks) {
            bf16x8 av[4], bv[4];
            #pragma unroll
            for (int mi = 0; mi < 4; ++mi) {
                int ar = wr * 64 + mi * 16 + lr;
                int q = (ks * 4 + lg) ^ (ar & 7);
                av[mi] = *(const bf16x8*)((const char*)lA + ar * 128 + q * 16);
            }
            #pragma unroll
            for (int ni = 0; ni < 4; ++ni) {
                int br = wc * 64 + ni * 16 + lr;
                int q = (ks * 4 + lg) ^ (br & 7);
                bv[ni] = *(const bf16x8*)((const char*)lB + br * 128 + q * 16);
            }
            #pragma unroll
            for (int mi = 0; mi < 4; ++mi)
                #pragma unroll
                for (int ni = 0; ni < 4; ++ni)
                    acc[mi][ni] = __builtin_amdgcn_mfma_f32_16x16x32_bf16(
                        av[mi], bv[ni], acc[mi][ni], 0, 0, 0);
        }
        __syncthreads();
    }
    const float* bp = biasv + (size_t)b * strideBias;
    int orow = row0 + wr * 64, ocol = col0 + wc * 64 + lr;
    #pragma unroll
    for (int mi = 0; mi < 4; ++mi) {
        int rb = orow + mi * 16 + lg * 4;
        float4 b4 = *(const float4*)&bp[rb];
        float bvr[4] = {b4.x, b4.y, b4.z, b4.w};
        #pragma unroll
        for (int ni = 0; ni < 4; ++ni) {
            int cc = ocol + ni * 16;
            #pragma unroll
            for (int r = 0; r < 4; ++r) {
                float v = acc[mi][ni][r] + bvr[r];
                if constexpr (OUTF32)
                    ((float*)Cmat + (size_t)b * strideC)[(size_t)(rb + r) * N + cc] = v;
                else
                    ((ushort*)Cmat + (size_t)b * strideC)[(size_t)(rb + r) * N + cc] = f2bf(v);
            }
        }
    }
}

// ---------------------------------------------------------------------------
// NT-GEMM bf16 MFMA 64x64 tile (higher occupancy for the small kv GEMM).
template<int K, int N, bool OUTF32>
__global__ __launch_bounds__(256) void nt_gemm64(const ushort* __restrict__ Amat, long long strideA,
                                                 const ushort* __restrict__ Bmat, long long strideB,
                                                 const float* __restrict__ biasv, int strideBias,
                                                 void* __restrict__ Cmat, long long strideC) {
    __shared__ ushort lA[64 * 64];
    __shared__ ushort lB[64 * 64];
    int b = blockIdx.z;
    int col0 = blockIdx.x * 64, row0 = blockIdx.y * 64;
    int t = threadIdx.x;
    int l = t & 63, wid = t >> 6;
    int wr = wid >> 1, wc = wid & 1;
    int lr = l & 15, lg = l >> 4;
    const ushort* Ab = Amat + (size_t)b * strideA + (size_t)row0 * K;
    const ushort* Bb = Bmat + (size_t)b * strideB + (size_t)col0 * K;
    f32x4 acc[2][2] = {};
    for (int k0 = 0; k0 < K; k0 += 64) {
        #pragma unroll
        for (int j = 0; j < 2; ++j) {
            int gi = j * 256 + t;
            int r = gi >> 3, g = (gi & 7) ^ (r & 7);
            gload16(Ab + (size_t)r * K + k0 + g * 8, (char*)lA + gi * 16);
        }
        #pragma unroll
        for (int j = 0; j < 2; ++j) {
            int gi = j * 256 + t;
            int r = gi >> 3, g = (gi & 7) ^ (r & 7);
            gload16(Bb + (size_t)r * K + k0 + g * 8, (char*)lB + gi * 16);
        }
        __syncthreads();
        #pragma unroll
        for (int ks = 0; ks < 2; ++ks) {
            bf16x8 av[2], bv[2];
            #pragma unroll
            for (int mi = 0; mi < 2; ++mi) {
                int ar = wr * 32 + mi * 16 + lr;
                int q = (ks * 4 + lg) ^ (ar & 7);
                av[mi] = *(const bf16x8*)((const char*)lA + ar * 128 + q * 16);
            }
            #pragma unroll
            for (int ni = 0; ni < 2; ++ni) {
                int br = wc * 32 + ni * 16 + lr;
                int q = (ks * 4 + lg) ^ (br & 7);
                bv[ni] = *(const bf16x8*)((const char*)lB + br * 128 + q * 16);
            }
            #pragma unroll
            for (int mi = 0; mi < 2; ++mi)
                #pragma unroll
                for (int ni = 0; ni < 2; ++ni)
                    acc[mi][ni] = __builtin_amdgcn_mfma_f32_16x16x32_bf16(
                        av[mi], bv[ni], acc[mi][ni], 0, 0, 0);
        }
        __syncthreads();
    }
    const float* bp = biasv + (size_t)b * strideBias;
    int orow = row0 + wr * 32, ocol = col0 + wc * 32 + lr;
    #pragma unroll
    for (int mi = 0; mi < 2; ++mi) {
        int rb = orow + mi * 16 + lg * 4;
        float4 b4 = *(const float4*)&bp[rb];
        float bvr[4] = {b4.x, b4.y, b4.z, b4.w};
        #pragma unroll
        for (int ni = 0; ni < 2; ++ni) {
            int cc = ocol + ni * 16;
            #pragma unroll
            for (int r = 0; r < 4; ++r) {
                float v = acc[mi][ni][r] + bvr[r];
                if constexpr (OUTF32)
                    ((float*)Cmat + (size_t)b * strideC)[(size_t)(rb + r) * N + cc] = v;
                else
                    ((ushort*)Cmat + (size_t)b * strideC)[(size_t)(rb + r) * N + cc] = f2bf(v);
            }
        }
    }
}

// ---------------------------------------------------------------------------
// Partial context, UNNORMALIZED: ctxU[d,e] += sum_n exp(k[d,n]) v[e,n],
// rowsum[d] += sum_n exp(k[d,n]).  grid (8 nchunks, 64 bh).
__global__ __launch_bounds__(256) void ctx_partial_kernel(const ushort* __restrict__ kv,
                                                          float* __restrict__ rowsum,
                                                          float* __restrict__ ctx) {
    int bh = blockIdx.y, b = bh >> 2, h = bh & 3;
    int n0 = blockIdx.x * 128;
    __shared__ float pl[32][129], vl[32][129];
    int t = threadIdx.x;
    int r = t >> 3, cs = (t & 7) * 16;
    const ushort* kp = kv + ((size_t)b * 256 + h * 32 + r) * 1024 + n0 + cs;
    const ushort* vp = kv + ((size_t)b * 256 + 128 + h * 32 + r) * 1024 + n0 + cs;
    float kvals[16], vvals[16];
    unpack8(((const uint4*)kp)[0], kvals);
    unpack8(((const uint4*)kp)[1], kvals + 8);
    unpack8(((const uint4*)vp)[0], vvals);
    unpack8(((const uint4*)vp)[1], vvals + 8);
    float psum = 0.f;
    #pragma unroll
    for (int i = 0; i < 16; ++i) {
        float e = __expf(kvals[i]);
        pl[r][cs + i] = e;
        vl[r][cs + i] = vvals[i];
        psum += e;
    }
    psum += __shfl_xor(psum, 1, 64);
    psum += __shfl_xor(psum, 2, 64);
    psum += __shfl_xor(psum, 4, 64);
    if ((t & 7) == 0) atomicAdd(&rowsum[bh * 32 + r], psum);
    __syncthreads();
    int d0 = t >> 5, e0 = t & 31;
    float acc[4] = {0.f, 0.f, 0.f, 0.f};
    #pragma unroll 8
    for (int nn = 0; nn < 128; ++nn) {
        float vv = vl[e0][nn];
        #pragma unroll
        for (int i = 0; i < 4; ++i)
            acc[i] += pl[d0 + 8 * i][nn] * vv;
    }
    #pragma unroll
    for (int i = 0; i < 4; ++i)
        atomicAdd(&ctx[((size_t)bh * 32 + d0 + 8 * i) * 32 + e0], acc[i]);
}

// ---------------------------------------------------------------------------
// A-fold: normalize ctx by rowsum, M = w_out@ctx^T in LDS, then
// A16[b,o,c] = bf16(wt*s), biasb[b,o] = sum_c wt*t + M.b_q + b_out
__global__ __launch_bounds__(256) void a_kernel(const float* __restrict__ ctx,
                                                const float* __restrict__ rowsum,
                                                const float* __restrict__ w_out,
                                                const float* __restrict__ w_q,
                                                const float* __restrict__ b_q,
                                                const float* __restrict__ statacc,
                                                const float* __restrict__ gn_w,
                                                const float* __restrict__ gn_b,
                                                const float* __restrict__ b_out,
                                                ushort* __restrict__ A16,
                                                float* __restrict__ biasb) {
    __shared__ float ctxl[4][32][33];
    __shared__ float wol[16][128];
    __shared__ float ml[16][128];
    __shared__ float cbuf[256][17];
    __shared__ float pbuf[16][17];
    int b = blockIdx.x >> 4, ot = (blockIdx.x & 15) << 4;
    int t = threadIdx.x;
    #pragma unroll
    for (int j = 0; j < 16; ++j) {
        int e = t + 256 * j;            // 0..4095
        float inv = 1.f / rowsum[b * 128 + (e >> 5)];
        ctxl[e >> 10][(e >> 5) & 31][e & 31] = ctx[(size_t)b * 4096 + e] * inv;
    }
    #pragma unroll
    for (int j = 0; j < 8; ++j) {
        int e = t + 256 * j;            // 0..2047
        wol[e >> 7][e & 127] = w_out[(ot + (e >> 7)) * 128 + (e & 127)];
    }
    __syncthreads();
    #pragma unroll
    for (int j = 0; j < 8; ++j) {
        int e = t + 256 * j;
        int o = e >> 7, hd = e & 127, h = hd >> 5, d = hd & 31;
        float acc = 0.f;
        #pragma unroll
        for (int ee = 0; ee < 32; ++ee) acc += wol[o][h * 32 + ee] * ctxl[h][d][ee];
        ml[o][hd] = acc;
    }
    __syncthreads();
    int c = t, g = c >> 3;
    float a0 = statacc[(b * 32 + g) * 2], a1 = statacc[(b * 32 + g) * 2 + 1];
    float mu  = a0 * (1.f / 32768.f);
    float var = a1 * (1.f / 32768.f) - mu * mu;
    float sc = rsqrtf(var + 1e-5f) * gn_w[c];
    float tc = gn_b[c] - mu * sc;
    float wt[16];
    #pragma unroll
    for (int o = 0; o < 16; ++o) wt[o] = 0.f;
    for (int hd = 0; hd < 128; ++hd) {
        float wq = w_q[hd * 256 + c];
        #pragma unroll
        for (int o = 0; o < 16; ++o) wt[o] += ml[o][hd] * wq;
    }
    ushort* Abp = A16 + ((size_t)b * 256 + ot) * 256 + c;
    #pragma unroll
    for (int o = 0; o < 16; ++o) {
        Abp[(size_t)o * 256] = f2bf(wt[o] * sc);
        cbuf[c][o] = wt[o] * tc;
    }
    __syncthreads();
    {
        int o = t >> 4, seg = t & 15;
        float p = 0.f;
        #pragma unroll
        for (int i = 0; i < 16; ++i) p += cbuf[seg * 16 + i][o];
        pbuf[o][seg] = p;
    }
    __syncthreads();
    if (t < 16) {
        int o = t;
        float sum = 0.f;
        #pragma unroll
        for (int s2 = 0; s2 < 16; ++s2) sum += pbuf[o][s2];
        float md = 0.f;
        #pragma unroll 8
        for (int hd = 0; hd < 128; ++hd) md += ml[o][hd] * b_q[hd];
        biasb[(size_t)b * 256 + ot + o] = sum + md + b_out[ot + o];
    }
}

extern "C" void kernel_launch(void* const* d_in, const int* in_sizes, int n_in,
                              void* d_out, int out_size, void* d_ws, size_t ws_size,
                              hipStream_t stream) {
    const float* x     = (const float*)d_in[0];
    const float* cond  = (const float*)d_in[1];
    const float* gn_w  = (const float*)d_in[2];
    const float* gn_b  = (const float*)d_in[3];
    const float* w_q   = (const float*)d_in[4];
    const float* b_q   = (const float*)d_in[5];
    const float* w_kv  = (const float*)d_in[6];
    const float* b_kv  = (const float*)d_in[7];
    const float* w_out = (const float*)d_in[8];
    const float* b_out = (const float*)d_in[9];
    float* out = (float*)d_out;

    float* f       = (float*)d_ws;
    float* statacc = f;                     // 1024 floats
    float* rowsum  = f + 1024;              // 2048 floats (contiguous zero range with statacc+ctx)
    float* ctx     = f + 3072;              // 65536 floats
    float* biasb   = f + 68608;             // 4096 floats
    ushort* u      = (ushort*)(f + 72704);
    ushort* wkv16  = u;                     // 131072
    ushort* kv16   = u + 131072;            // 4194304
    ushort* A16    = u + 4325376;           // 1048576
    ushort* xT     = u + 5373952;           // 16777216
    ushort* condT  = u + 22151168;          // 8388608

    // L1: zero accumulators + convert w_kv (precedes all atomics in stream order)
    cvtw_kernel<<<512, 256, 0, stream>>>(w_kv, wkv16, statacc);
    // L2: merged transposes (x w/ GN stats, cond)
    tpose_kernel<<<6144, 256, 0, stream>>>(x, cond, xT, condT, statacc);
    // L3: kv = w_kv @ cond  (64x64 tiles, 1024 blocks)
    nt_gemm64<512, 1024, false><<<dim3(16, 4, 16), 256, 0, stream>>>(
        wkv16, 0, condT, (long long)512 * 1024, b_kv, 0, kv16, (long long)256 * 1024);
    // L4: unnormalized context + row sums
    ctx_partial_kernel<<<dim3(8, 64), 256, 0, stream>>>(kv16, rowsum, ctx);
    // L5: fold everything into per-batch A (bf16) + bias
    a_kernel<<<256, 256, 0, stream>>>(ctx, rowsum, w_out, w_q, b_q, statacc,
                                      gn_w, gn_b, b_out, A16, biasb);
    // L6: out = A @ x^T + bias
    nt_gemm<256, 4096, true><<<dim3(32, 2, 16), 256, 0, stream>>>(
        A16, 65536, xT, (long long)4096 * 256, biasb, 256, out, (long long)256 * 4096);
}